// Round 4
// baseline (807.736 us; speedup 1.0000x reference)
//
#include <hip/hip_runtime.h>

// mLSTM  S=256 B=64 F=H=512 L=4
// v4: gemm XOR-swizzled LDS (kill 8-way ds_read conflicts) + LN-stats partials
//     fused into the gemm epilogue (stats_k deleted; tiny stats2_k finalizes).
//   gemm_k   : Z = A @ W^T + bias (bf16 MFMA) + per-(row,ntile) {sum,sumsq,wk}
//   stats2_k : finalize mu/rstd/sumk per row (reads 3.4MB partials, not 100MB Z)
//   scanA_k  : chunk-local scans (16-step), P_t = prod f stored
//   scanB_k  : exact fp32 cross-chunk combine -> n0/chunk
//   normh_k  : n_t = n_loc + P_t*n0 ; ||n|| reduce ; h = o*tanh(q*n_hat) + res

typedef unsigned short u16;
typedef unsigned int   u32;
typedef short s8v __attribute__((ext_vector_type(8)));   // 8 x bf16 (4 VGPRs)
typedef float f4v __attribute__((ext_vector_type(4)));   // MFMA accum

#define S_    256
#define B_    64
#define F_    512
#define H_    512
#define L_    4
#define NG    3072          // 6*H
#define RALL  16384         // S*B
#define CH    16            // scan chunk length
#define INV_SQRT_H 0.044194173824159216f

__device__ __forceinline__ float bu2f(u16 u) {
    union { u32 i; float f; } z; z.i = ((u32)u) << 16; return z.f;
}
__device__ __forceinline__ u16 f2bf(float f) {
    union { float f; u32 i; } z; z.f = f;
    u32 r = (z.i + 0x7FFFu + ((z.i >> 16) & 1u)) >> 16;
    return (u16)r;
}
__device__ __forceinline__ float sigm(float x)  { return 1.0f / (1.0f + __expf(-x)); }
__device__ __forceinline__ float tanhf_(float x){ return 2.0f / (1.0f + __expf(-2.0f * x)) - 1.0f; }
__device__ __forceinline__ float wred64(float v) {
    #pragma unroll
    for (int m = 1; m < 64; m <<= 1) v += __shfl_xor(v, m);
    return v;
}
__device__ __forceinline__ void gl_lds16(const u16* g, u16* l) {
    __builtin_amdgcn_global_load_lds((const __attribute__((address_space(1))) u32*)g,
                                     (__attribute__((address_space(3))) u32*)l, 16, 0, 0);
}
__device__ __forceinline__ void unp8(uint4 u, float* f) {
    f[0] = bu2f((u16)(u.x & 0xffff)); f[1] = bu2f((u16)(u.x >> 16));
    f[2] = bu2f((u16)(u.y & 0xffff)); f[3] = bu2f((u16)(u.y >> 16));
    f[4] = bu2f((u16)(u.z & 0xffff)); f[5] = bu2f((u16)(u.z >> 16));
    f[6] = bu2f((u16)(u.w & 0xffff)); f[7] = bu2f((u16)(u.w >> 16));
}
__device__ __forceinline__ uint4 pck8(const float* f) {
    uint4 u;
    u.x = (u32)f2bf(f[0]) | ((u32)f2bf(f[1]) << 16);
    u.y = (u32)f2bf(f[2]) | ((u32)f2bf(f[3]) << 16);
    u.z = (u32)f2bf(f[4]) | ((u32)f2bf(f[5]) << 16);
    u.w = (u32)f2bf(f[6]) | ((u32)f2bf(f[7]) << 16);
    return u;
}

// ---- W [L,6,F,H] fp32 -> WT [L,6,H,F] bf16 (transpose via LDS tile) ----
__global__ void convw_k(const float* __restrict__ W, u16* __restrict__ WT) {
    __shared__ float tile[32][33];
    const int lg = blockIdx.z;                  // 0..23
    const int h0 = blockIdx.x * 32, f0 = blockIdx.y * 32;
    const float* Wb = W  + (size_t)lg * F_ * H_;
    u16*        WTb = WT + (size_t)lg * F_ * H_;
    const int tx = threadIdx.x, ty = threadIdx.y;  // 32x8
    #pragma unroll
    for (int i = 0; i < 32; i += 8)
        tile[ty + i][tx] = Wb[(size_t)(f0 + ty + i) * H_ + h0 + tx];
    __syncthreads();
    #pragma unroll
    for (int i = 0; i < 32; i += 8)
        WTb[(size_t)(h0 + ty + i) * F_ + f0 + tx] = f2bf(tile[tx][ty + i]);
}

// ---- x fp32 -> A bf16 ----
__global__ void convx_k(const float* __restrict__ x, u16* __restrict__ A) {
    const int i = blockIdx.x * 256 + threadIdx.x;   // covers RALL*F/4 exactly
    float4 v = ((const float4*)x)[i];
    u32 lo = (u32)f2bf(v.x) | ((u32)f2bf(v.y) << 16);
    u32 hi = (u32)f2bf(v.z) | ((u32)f2bf(v.w) << 16);
    ((uint2*)A)[i] = make_uint2(lo, hi);
}

// ---- sum of ln_g[l][1][:] and ln_b[l][1][:] per layer (one wave per layer) ----
__global__ void sumgb_k(const float* __restrict__ lng, const float* __restrict__ lnb,
                        float* __restrict__ sgb) {
    const int l = blockIdx.x, lane = threadIdx.x;
    float s = 0.f, b = 0.f;
    #pragma unroll
    for (int j = 0; j < 8; j++) {
        s += lng[(size_t)l * 6 * 512 + 512 + j * 64 + lane];
        b += lnb[(size_t)l * 6 * 512 + 512 + j * 64 + lane];
    }
    s = wred64(s); b = wred64(b);
    if (lane == 0) { sgb[l * 2] = s; sgb[l * 2 + 1] = b; }
}

// ---- GEMM: Z[m, 3072] = A @ WT^T + bias; fused LN-stat partials per 128-tile ----
// LDS XOR swizzle at 16B granule: granule(row,kc) = row*4 + (kc ^ ((row>>1)&3)).
__global__ __launch_bounds__(256) void gemm_k(const u16* __restrict__ A,
                                              const u16* __restrict__ BT,
                                              u16* __restrict__ Z,
                                              const float* __restrict__ bias,
                                              const float* __restrict__ lng1,   // ln_g[l][1][:]
                                              float2* __restrict__ spart,       // [rows][24]
                                              float* __restrict__ wkpart,       // [rows][4]
                                              int arow0) {
    __shared__ u16 lsA[128 * 32];
    __shared__ u16 lsB[128 * 32];
    __shared__ float sred[128][2][3];
    const int t = threadIdx.x;
    const int ntile = blockIdx.x;                  // 0..23
    const int mtile = blockIdx.y;
    const int ncol0 = ntile * 128;
    const u16* Ab = A  + (size_t)(arow0 + mtile * 128) * F_;
    const u16* Bb = BT + (size_t)ntile * 128 * F_;
    const int lane = t & 63, wv = t >> 6;

    f4v acc[4][4];
    #pragma unroll
    for (int i = 0; i < 4; i++)
        #pragma unroll
        for (int j = 0; j < 4; j++) acc[i][j] = 0.0f;

    const int wm = (wv >> 1) * 64, wn = (wv & 1) * 64;
    const int ro = lane & 15, kq = lane >> 4;
    const int swz = ((ro >> 1) & 3) ^ kq;          // lane-constant read swizzle

    // staging chunk params (global side carries the inverse swizzle)
    const int r0 = t >> 2,          kc0 = (t & 3)         ^ ((r0 >> 1) & 3);
    const int r1 = (t + 256) >> 2,  kc1 = ((t + 256) & 3) ^ ((r1 >> 1) & 3);

    for (int kb = 0; kb < 16; ++kb) {
        gl_lds16(Ab + (size_t)r0 * F_ + kb * 32 + kc0 * 8, lsA + t * 8);
        gl_lds16(Bb + (size_t)r0 * F_ + kb * 32 + kc0 * 8, lsB + t * 8);
        gl_lds16(Ab + (size_t)r1 * F_ + kb * 32 + kc1 * 8, lsA + (t + 256) * 8);
        gl_lds16(Bb + (size_t)r1 * F_ + kb * 32 + kc1 * 8, lsB + (t + 256) * 8);
        __syncthreads();
        s8v fa[4], fb[4];
        #pragma unroll
        for (int i = 0; i < 4; i++) fa[i] = *(const s8v*)(lsA + (wm + i * 16 + ro) * 32 + swz * 8);
        #pragma unroll
        for (int j = 0; j < 4; j++) fb[j] = *(const s8v*)(lsB + (wn + j * 16 + ro) * 32 + swz * 8);
        #pragma unroll
        for (int i = 0; i < 4; i++)
            #pragma unroll
            for (int j = 0; j < 4; j++)
                acc[i][j] = __builtin_amdgcn_mfma_f32_16x16x32_bf16(fa[i], fb[j], acc[i][j], 0, 0, 0);
        __syncthreads();
    }

    // epilogue: store Z (bf16) + per-row {sum, sumsq, wk} partial reductions.
    // C/D layout col=lane&15, row=(lane>>4)*4+reg.
    const int cl = lane & 15, rq = kq * 4;
    const int gate = ncol0 >> 9;                   // 128-col tile sits in one gate
    float g1v[4] = {0.f, 0.f, 0.f, 0.f};
    if (gate == 1) {
        #pragma unroll
        for (int j = 0; j < 4; j++) g1v[j] = lng1[ncol0 - 512 + wn + j * 16 + cl];
    }
    #pragma unroll
    for (int i = 0; i < 4; i++) {
        float sv[4] = {0, 0, 0, 0}, qv[4] = {0, 0, 0, 0}, wvv[4] = {0, 0, 0, 0};
        const int mbase = mtile * 128 + wm + i * 16 + rq;
        #pragma unroll
        for (int j = 0; j < 4; j++) {
            const int col = ncol0 + wn + j * 16 + cl;
            const float bv = bias[col];
            #pragma unroll
            for (int r2 = 0; r2 < 4; r2++) {
                const float v = acc[i][j][r2] + bv;
                Z[(size_t)(mbase + r2) * NG + col] = f2bf(v);
                sv[r2] += v; qv[r2] += v * v;
                if (gate == 1) wvv[r2] += g1v[j] * v;
            }
        }
        #pragma unroll
        for (int r2 = 0; r2 < 4; r2++) {
            #pragma unroll
            for (int m = 1; m < 16; m <<= 1) {
                sv[r2]  += __shfl_xor(sv[r2], m);
                qv[r2]  += __shfl_xor(qv[r2], m);
                if (gate == 1) wvv[r2] += __shfl_xor(wvv[r2], m);
            }
            if (cl == 0) {
                const int rl = wm + i * 16 + rq + r2;
                sred[rl][wn >> 6][0] = sv[r2];
                sred[rl][wn >> 6][1] = qv[r2];
                sred[rl][wn >> 6][2] = (gate == 1) ? wvv[r2] : 0.f;
            }
        }
    }
    __syncthreads();
    if (t < 128) {
        const int row = mtile * 128 + t;
        spart[(size_t)row * 24 + ntile] =
            make_float2(sred[t][0][0] + sred[t][1][0], sred[t][0][1] + sred[t][1][1]);
        if (gate == 1)
            wkpart[(size_t)row * 4 + (ntile - 4)] = sred[t][0][2] + sred[t][1][2];
    }
}

// ---- stats finalize: one thread per row; reads 24 partial pairs + 4 wk. ----
__global__ __launch_bounds__(256) void stats2_k(const float2* __restrict__ spart,
                                                const float* __restrict__ wkpart,
                                                const float* __restrict__ sgb,  // this layer's {sg1,sb1}
                                                float* __restrict__ stats) {
    const int row = blockIdx.x * 256 + threadIdx.x;
    const float2* sp = spart + (size_t)row * 24;
    float* o = stats + (size_t)row * 16;
    const float inv = 1.0f / 512.0f;
    float mu1 = 0.f, rs1 = 0.f;
    #pragma unroll
    for (int g = 0; g < 6; ++g) {
        float ss = 0.f, qq = 0.f;
        #pragma unroll
        for (int u = 0; u < 4; u++) { const float2 v = sp[g * 4 + u]; ss += v.x; qq += v.y; }
        float m = ss * inv, e2 = qq * inv;
        if (g == 1) { m *= INV_SQRT_H; e2 *= INV_SQRT_H * INV_SQRT_H; }
        const float rs = rsqrtf(fmaxf(e2 - m * m, 0.0f) + 1e-5f);
        o[g] = m; o[6 + g] = rs;
        if (g == 1) { mu1 = m; rs1 = rs; }
    }
    const float wk = wkpart[(size_t)row * 4] + wkpart[(size_t)row * 4 + 1] +
                     wkpart[(size_t)row * 4 + 2] + wkpart[(size_t)row * 4 + 3];
    o[12] = rs1 * (INV_SQRT_H * wk - mu1 * sgb[0]) + sgb[1];
}

// ---- scanA: chunk-local scan from zero state. One thread per (chunk,b,h). ----
__global__ __launch_bounds__(128) void scanA_k(const u16* __restrict__ Z,
                                               const float* __restrict__ stats,
                                               const float* __restrict__ lngl,
                                               const float* __restrict__ lnbl,
                                               u16* __restrict__ nbuf,
                                               u16* __restrict__ pbuf,
                                               float* __restrict__ sumP,
                                               float* __restrict__ sumC,
                                               float* __restrict__ sumN) {
    const int b = blockIdx.y, chunk = blockIdx.z;
    const int h = blockIdx.x * 128 + threadIdx.x;
    __shared__ float sst[CH][16];
    for (int i = threadIdx.x; i < CH * 16; i += 128) {
        const int tc = i >> 4, j = i & 15;
        sst[tc][j] = stats[(size_t)((chunk * CH + tc) * 64 + b) * 16 + j];
    }
    float gg[4], gb[4];
    #pragma unroll
    for (int g = 0; g < 4; ++g) {
        gg[g] = lngl[(g + 1) * 512 + h];
        gb[g] = lnbl[(g + 1) * 512 + h];
    }
    __syncthreads();

    float c = 0.f, n = 0.f, P = 1.f;
    #pragma unroll 4
    for (int tc = 0; tc < CH; ++tc) {
        const int r = (chunk * CH + tc) * 64 + b;
        const u16* zr = Z + (size_t)r * NG + h;
        const float z1 = bu2f(zr[512]);
        const float z2 = bu2f(zr[1024]);
        const float z3 = bu2f(zr[1536]);
        const float z4 = bu2f(zr[2048]);
        const float kk = (z1 * INV_SQRT_H - sst[tc][1]) * sst[tc][7] * gg[0] + gb[0];
        const float vv = (z2 - sst[tc][2]) * sst[tc][8]  * gg[1] + gb[1];
        const float ii = sigm((z3 - sst[tc][3]) * sst[tc][9]  * gg[2] + gb[2]);
        const float ff = sigm((z4 - sst[tc][4]) * sst[tc][10] * gg[3] + gb[3]);
        c = ff * c + ii * (sst[tc][12] * vv);
        n = ff * n + ii * kk;
        P *= ff;
        nbuf[(size_t)r * 512 + h] = f2bf(n);
        pbuf[(size_t)r * 512 + h] = f2bf(P);
    }
    const size_t idx = ((size_t)chunk << 15) + (b << 9) + h;
    sumP[idx] = P; sumC[idx] = c; sumN[idx] = n;
}

// ---- scanB: exact fp32 combine across chunks; emits per-chunk incoming n0. ----
__global__ __launch_bounds__(256) void scanB_k(const float* __restrict__ sumP,
                                               const float* __restrict__ sumC,
                                               const float* __restrict__ sumN,
                                               float* __restrict__ n0buf,
                                               float* __restrict__ cstate,
                                               float* __restrict__ nstate,
                                               float* __restrict__ finals,
                                               int t0, int NC, int l) {
    const int idx = blockIdx.x * 256 + threadIdx.x;   // 0..32767
    float c, n;
    if (t0 == 0) { c = 0.f; n = 0.f; }
    else { c = cstate[idx]; n = nstate[idx]; }
    for (int ch = 0; ch < NC; ++ch) {
        const size_t o = ((size_t)ch << 15) + idx;
        n0buf[o] = n;
        const float P = sumP[o];
        c = sumC[o] + P * c;
        n = sumN[o] + P * n;
    }
    if (t0 + NC * CH == S_) {
        const int b = idx >> 9, h = idx & 511;
        const size_t so = ((size_t)l * B_ + b) * H_ + h;
        finals[(size_t)L_ * B_ * H_ + so] = c;       // c final (exact fp32 combine)
        finals[(size_t)2 * L_ * B_ * H_ + so] = n;   // n final
    } else {
        cstate[idx] = c; nstate[idx] = n;
    }
}

// ---- normh: one wave per (t,b) row. n = n_loc + P*n0; ||n|| reduce; h. ----
__global__ __launch_bounds__(256) void normh_k(const u16* __restrict__ Z,
                                               const u16* __restrict__ nbuf,
                                               const u16* __restrict__ pbuf,
                                               const float* __restrict__ n0buf,
                                               const float* __restrict__ stats,
                                               const float* __restrict__ lngl,
                                               const float* __restrict__ lnbl,
                                               float* __restrict__ hbuf,
                                               u16* __restrict__ aoutB,  // null for l==3
                                               float* __restrict__ outp, // null for l<3
                                               float* __restrict__ finals,
                                               int t0, int l) {
    const int wid = threadIdx.x >> 6, lane = threadIdx.x & 63;
    const int r = blockIdx.x * 4 + wid;
    const int h0 = lane * 8;

    float nl[8], pv[8];
    unp8(*(const uint4*)(nbuf + (size_t)r * 512 + h0), nl);
    unp8(*(const uint4*)(pbuf + (size_t)r * 512 + h0), pv);
    const float* n0r = n0buf + ((size_t)(r >> 10) << 15) + ((size_t)(r & 63) << 9) + h0;
    const float4 na = *(const float4*)(n0r);
    const float4 nb = *(const float4*)(n0r + 4);
    const float n0v[8] = {na.x, na.y, na.z, na.w, nb.x, nb.y, nb.z, nb.w};

    float nv[8], nsq = 0.f;
    #pragma unroll
    for (int j = 0; j < 8; j++) {
        nv[j] = fmaf(pv[j], n0v[j], nl[j]);
        nsq += nv[j] * nv[j];
    }
    nsq = wred64(nsq);
    const float rinv = 1.0f / (sqrtf(nsq) + 1e-8f);

    const u16* zr = Z + (size_t)r * NG;
    float z0[8], z5[8];
    unp8(*(const uint4*)(zr + h0), z0);
    unp8(*(const uint4*)(zr + 2560 + h0), z5);

    const float* st = stats + (size_t)r * 16;
    const float mu0 = st[0], rs0 = st[6], mu5 = st[5], rs5 = st[11];

    float g0[8], b0[8], g5[8], b5[8];
    #pragma unroll
    for (int j = 0; j < 8; j++) {
        g0[j] = lngl[h0 + j];        b0[j] = lnbl[h0 + j];
        g5[j] = lngl[2560 + h0 + j]; b5[j] = lnbl[2560 + h0 + j];
    }

    const int tl = r >> 6, b = r & 63;
    const int gr = t0 + tl;
    const size_t grow = (((size_t)gr * 64 + b) * 512) + h0;

    float hv[8];
    #pragma unroll
    for (int j = 0; j < 8; j++) {
        const float q  = (z0[j] - mu0) * rs0 * g0[j] + b0[j];
        const float oo = sigm((z5[j] - mu5) * rs5 * g5[j] + b5[j]);
        hv[j] = oo * tanhf_(q * nv[j] * rinv);
    }
    if (l > 0) {
        #pragma unroll
        for (int j = 0; j < 8; j++) hv[j] += hbuf[grow + j];
    }
    if (outp) {
        #pragma unroll
        for (int j = 0; j < 8; j++) outp[grow + j] = hv[j];
    } else {
        #pragma unroll
        for (int j = 0; j < 8; j++) hbuf[grow + j] = hv[j];
    }
    if (aoutB) *(uint4*)(aoutB + grow) = pck8(hv);

    if (gr == S_ - 1) {
        const size_t so = (((size_t)l * B_ + b) * 512) + h0;
        #pragma unroll
        for (int j = 0; j < 8; j++) finals[so + j] = hv[j];
    }
}

extern "C" void kernel_launch(void* const* d_in, const int* in_sizes, int n_in,
                              void* d_out, int out_size, void* d_ws, size_t ws_size,
                              hipStream_t stream) {
    const float* x   = (const float*)d_in[0];
    const float* W   = (const float*)d_in[1];
    const float* bia = (const float*)d_in[2];
    const float* lng = (const float*)d_in[3];
    const float* lnb = (const float*)d_in[4];
    float* out = (float*)d_out;

    const size_t WT_B = (size_t)L_ * 6 * H_ * F_ * 2;   // 12.58 MB
    const size_t A_B  = (size_t)RALL * F_ * 2;          // 16.78 MB
    const size_t ST_B = (size_t)RALL * 16 * 4;          // 1.05 MB
    const size_t SP_B = (size_t)RALL * 24 * 8;          // 3.15 MB (float2 partials)
    const size_t WK_B = (size_t)RALL * 4 * 4;           // 0.26 MB
    const size_t CS_B = (size_t)B_ * H_ * 4;            // 128 KB
    const size_t HB_B = (size_t)RALL * H_ * 4;          // 33.55 MB
    auto zB  = [](int T) { return (size_t)T * B_ * NG * 2; };
    auto nB  = [](int T) { return (size_t)T * B_ * H_ * 2; };
    auto cxB = [](int T) { return (size_t)(T / CH) * B_ * H_ * 4; };
    const size_t base = WT_B + A_B + ST_B + SP_B + WK_B + 2 * CS_B + HB_B + 65536;

    int T = 16;
    const int cand[3] = {256, 64, 16};
    for (int i = 0; i < 3; i++) {
        const int Tc = cand[i];
        if (ws_size >= base + zB(Tc) + 2 * nB(Tc) + 4 * cxB(Tc)) { T = Tc; break; }
    }
    const int NC = T / CH;

    char* ws = (char*)d_ws;
    size_t off = 0;
    auto take = [&](size_t nb) { size_t o = off; off += (nb + 255) & ~(size_t)255; return o; };
    u16*   WT    = (u16*)  (ws + take(WT_B));
    u16*   Abf   = (u16*)  (ws + take(A_B));
    float* stats = (float*)(ws + take(ST_B));
    float2* spart= (float2*)(ws + take(SP_B));
    float* wkprt = (float*)(ws + take(WK_B));
    float* sgb   = (float*)(ws + take(256));
    float* cs    = (float*)(ws + take(CS_B));
    float* ns    = (float*)(ws + take(CS_B));
    float* hbuf  = (float*)(ws + take(HB_B));
    u16*   zb    = (u16*)  (ws + take(zB(T)));
    u16*   nbuf  = (u16*)  (ws + take(nB(T)));
    u16*   pbuf  = (u16*)  (ws + take(nB(T)));
    float* sumP  = (float*)(ws + take(cxB(T)));
    float* sumC  = (float*)(ws + take(cxB(T)));
    float* sumN  = (float*)(ws + take(cxB(T)));
    float* n0buf = (float*)(ws + take(cxB(T)));

    convw_k<<<dim3(16, 16, 24), dim3(32, 8), 0, stream>>>(W, WT);
    convx_k<<<dim3(RALL * F_ / 4 / 256), dim3(256), 0, stream>>>(x, Abf);
    sumgb_k<<<dim3(L_), dim3(64), 0, stream>>>(lng, lnb, sgb);

    float* finals = out + (size_t)S_ * B_ * H_;
    for (int l = 0; l < L_; ++l) {
        const u16*   WTl   = WT  + (size_t)l * 6 * H_ * F_;
        const float* biasl = bia + (size_t)l * NG;
        const float* lngl  = lng + (size_t)l * 6 * H_;
        const float* lnbl  = lnb + (size_t)l * 6 * H_;
        for (int j = 0; j < S_ / T; ++j) {
            const int t0 = j * T, arow0 = t0 * B_;
            const int rows = T * B_;
            gemm_k<<<dim3(24, rows / 128), dim3(256), 0, stream>>>(Abf, WTl, zb, biasl,
                                                                   lngl + H_, spart, wkprt, arow0);
            stats2_k<<<dim3(rows / 256), dim3(256), 0, stream>>>(spart, wkprt, sgb + l * 2, stats);
            scanA_k<<<dim3(4, B_, NC), dim3(128), 0, stream>>>(zb, stats, lngl, lnbl,
                                                               nbuf, pbuf, sumP, sumC, sumN);
            scanB_k<<<dim3(128), dim3(256), 0, stream>>>(sumP, sumC, sumN, n0buf,
                                                         cs, ns, finals, t0, NC, l);
            normh_k<<<dim3(rows / 4), dim3(256), 0, stream>>>(zb, nbuf, pbuf, n0buf, stats,
                                                              lngl, lnbl, hbuf,
                                                              (l < 3) ? Abf : (u16*)nullptr,
                                                              (l == 3) ? out : (float*)nullptr,
                                                              finals, t0, l);
        }
    }
}

// Round 5
// 680.124 us; speedup vs baseline: 1.1876x; 1.1876x over previous
//
#include <hip/hip_runtime.h>

// mLSTM  S=256 B=64 F=H=512 L=4
// v5: round-3 structure (separate stats_k, simple gemm epilogue) + gemm K-loop
//     rebuilt with BK=64 and a 16B-granule XOR swizzle (conflict-free ds_read_b128,
//     half the barrier drains).
//   gemm_k  : Z = A @ W^T + bias (bf16 MFMA, 128x128 tile, BK=64, swizzled LDS)
//   stats_k : LN mu/rstd per (row,gate) + sum_k   (z-only)
//   scanA_k : chunk-local scans (16-step), P_t = prod f stored
//   scanB_k : exact fp32 cross-chunk combine -> n0/chunk
//   normh_k : n_t = n_loc + P_t*n0 ; ||n|| reduce ; h = o*tanh(q*n_hat) + res

typedef unsigned short u16;
typedef unsigned int   u32;
typedef short s8v __attribute__((ext_vector_type(8)));   // 8 x bf16 (4 VGPRs)
typedef float f4v __attribute__((ext_vector_type(4)));   // MFMA accum

#define S_    256
#define B_    64
#define F_    512
#define H_    512
#define L_    4
#define NG    3072          // 6*H
#define RALL  16384         // S*B
#define CH    16            // scan chunk length
#define INV_SQRT_H 0.044194173824159216f

__device__ __forceinline__ float bu2f(u16 u) {
    union { u32 i; float f; } z; z.i = ((u32)u) << 16; return z.f;
}
__device__ __forceinline__ u16 f2bf(float f) {
    union { float f; u32 i; } z; z.f = f;
    u32 r = (z.i + 0x7FFFu + ((z.i >> 16) & 1u)) >> 16;
    return (u16)r;
}
__device__ __forceinline__ float sigm(float x)  { return 1.0f / (1.0f + __expf(-x)); }
__device__ __forceinline__ float tanhf_(float x){ return 2.0f / (1.0f + __expf(-2.0f * x)) - 1.0f; }
__device__ __forceinline__ float wred64(float v) {
    #pragma unroll
    for (int m = 1; m < 64; m <<= 1) v += __shfl_xor(v, m);
    return v;
}
__device__ __forceinline__ void gl_lds16(const u16* g, u16* l) {
    __builtin_amdgcn_global_load_lds((const __attribute__((address_space(1))) u32*)g,
                                     (__attribute__((address_space(3))) u32*)l, 16, 0, 0);
}
__device__ __forceinline__ void unp8(uint4 u, float* f) {
    f[0] = bu2f((u16)(u.x & 0xffff)); f[1] = bu2f((u16)(u.x >> 16));
    f[2] = bu2f((u16)(u.y & 0xffff)); f[3] = bu2f((u16)(u.y >> 16));
    f[4] = bu2f((u16)(u.z & 0xffff)); f[5] = bu2f((u16)(u.z >> 16));
    f[6] = bu2f((u16)(u.w & 0xffff)); f[7] = bu2f((u16)(u.w >> 16));
}
__device__ __forceinline__ uint4 pck8(const float* f) {
    uint4 u;
    u.x = (u32)f2bf(f[0]) | ((u32)f2bf(f[1]) << 16);
    u.y = (u32)f2bf(f[2]) | ((u32)f2bf(f[3]) << 16);
    u.z = (u32)f2bf(f[4]) | ((u32)f2bf(f[5]) << 16);
    u.w = (u32)f2bf(f[6]) | ((u32)f2bf(f[7]) << 16);
    return u;
}

// ---- W [L,6,F,H] fp32 -> WT [L,6,H,F] bf16 (transpose via LDS tile) ----
__global__ void convw_k(const float* __restrict__ W, u16* __restrict__ WT) {
    __shared__ float tile[32][33];
    const int lg = blockIdx.z;                  // 0..23
    const int h0 = blockIdx.x * 32, f0 = blockIdx.y * 32;
    const float* Wb = W  + (size_t)lg * F_ * H_;
    u16*        WTb = WT + (size_t)lg * F_ * H_;
    const int tx = threadIdx.x, ty = threadIdx.y;  // 32x8
    #pragma unroll
    for (int i = 0; i < 32; i += 8)
        tile[ty + i][tx] = Wb[(size_t)(f0 + ty + i) * H_ + h0 + tx];
    __syncthreads();
    #pragma unroll
    for (int i = 0; i < 32; i += 8)
        WTb[(size_t)(h0 + ty + i) * F_ + f0 + tx] = f2bf(tile[tx][ty + i]);
}

// ---- x fp32 -> A bf16 ----
__global__ void convx_k(const float* __restrict__ x, u16* __restrict__ A) {
    const int i = blockIdx.x * 256 + threadIdx.x;   // covers RALL*F/4 exactly
    float4 v = ((const float4*)x)[i];
    u32 lo = (u32)f2bf(v.x) | ((u32)f2bf(v.y) << 16);
    u32 hi = (u32)f2bf(v.z) | ((u32)f2bf(v.w) << 16);
    ((uint2*)A)[i] = make_uint2(lo, hi);
}

// ---- GEMM: Z[m, 3072] = A @ WT^T + bias. 128x128 tile, BK=64, swizzled LDS. ----
// LDS layout: 128 rows x 8 slots of 8 bf16 (16B). Slot s of row r holds global
// chunk g = s ^ (r&7). Read: slot = g ^ (r&7). 8 consecutive lanes of a
// ds_read_b128 hit 8 distinct 4-bank groups -> conflict-free.
__global__ __launch_bounds__(256) void gemm_k(const u16* __restrict__ A,
                                              const u16* __restrict__ BT,
                                              u16* __restrict__ Z,
                                              const float* __restrict__ bias,
                                              int arow0) {
    __shared__ u16 lsA[128 * 64];
    __shared__ u16 lsB[128 * 64];
    const int t = threadIdx.x;
    const int ntile = blockIdx.x;                  // 0..23
    const int mtile = blockIdx.y;
    const int ncol0 = ntile * 128;
    const u16* Ab = A  + (size_t)(arow0 + mtile * 128) * F_;
    const u16* Bb = BT + (size_t)ntile * 128 * F_;
    const int lane = t & 63, wv = t >> 6;

    f4v acc[4][4];
    #pragma unroll
    for (int i = 0; i < 4; i++)
        #pragma unroll
        for (int j = 0; j < 4; j++) acc[i][j] = 0.0f;

    const int wm = (wv >> 1) * 64, wn = (wv & 1) * 64;
    const int ro = lane & 15, kq = lane >> 4;
    // lane-constant read slots for the two K-halves
    const int slot0 = kq ^ (ro & 7);
    const int slot1 = (kq + 4) ^ (ro & 7);

    // staging: 4 chunks each for A and B per thread per kb-iter
    int goff[4];
    #pragma unroll
    for (int s = 0; s < 4; s++) {
        const int c = t + 256 * s;
        const int row = c >> 3, slot = c & 7;
        const int g = slot ^ (row & 7);
        goff[s] = row * F_ + g * 8;
    }

    for (int kb = 0; kb < 8; ++kb) {
        const int kofs = kb * 64;
        #pragma unroll
        for (int s = 0; s < 4; s++) {
            const int c = t + 256 * s;
            gl_lds16(Ab + goff[s] + kofs, lsA + c * 8);
            gl_lds16(Bb + goff[s] + kofs, lsB + c * 8);
        }
        __syncthreads();
        #pragma unroll
        for (int kk = 0; kk < 2; ++kk) {
            const int slot = kk ? slot1 : slot0;
            s8v fa[4], fb[4];
            #pragma unroll
            for (int i = 0; i < 4; i++)
                fa[i] = *(const s8v*)(lsA + (wm + i * 16 + ro) * 64 + slot * 8);
            #pragma unroll
            for (int j = 0; j < 4; j++)
                fb[j] = *(const s8v*)(lsB + (wn + j * 16 + ro) * 64 + slot * 8);
            #pragma unroll
            for (int i = 0; i < 4; i++)
                #pragma unroll
                for (int j = 0; j < 4; j++)
                    acc[i][j] = __builtin_amdgcn_mfma_f32_16x16x32_bf16(fa[i], fb[j], acc[i][j], 0, 0, 0);
        }
        __syncthreads();
    }

    // epilogue: C/D layout col=lane&15, row=(lane>>4)*4+reg
    const int cl = lane & 15, rq = kq * 4;
    #pragma unroll
    for (int j = 0; j < 4; j++) {
        const int col = ncol0 + wn + j * 16 + cl;
        const float bv = bias[col];
        #pragma unroll
        for (int i = 0; i < 4; i++) {
            const int mbase = mtile * 128 + wm + i * 16 + rq;
            #pragma unroll
            for (int r2 = 0; r2 < 4; r2++)
                Z[(size_t)(mbase + r2) * NG + col] = f2bf(acc[i][j][r2] + bv);
        }
    }
}

// ---- stats: per row (t,b): LN mu/rstd for 6 gates + sum_k. One wave per row. ----
__global__ __launch_bounds__(256) void stats_k(const u16* __restrict__ Z,
                                               const float* __restrict__ lng1,
                                               const float* __restrict__ lnb1,
                                               float* __restrict__ stats) {
    const int wid = threadIdx.x >> 6, lane = threadIdx.x & 63;
    const int row = blockIdx.x * 4 + wid;
    const u16* zr = Z + (size_t)row * NG + lane * 8;

    float g1v[8], b1v[8];
    #pragma unroll
    for (int j = 0; j < 8; j++) { g1v[j] = lng1[lane * 8 + j]; b1v[j] = lnb1[lane * 8 + j]; }

    float s[6], sq[6], wk = 0.f, sg1 = 0.f, sb1 = 0.f;
    #pragma unroll
    for (int g = 0; g < 6; ++g) {
        uint4 u = *(const uint4*)(zr + g * 512);
        float f[8];
        unp8(u, f);
        float ls = 0.f, lq = 0.f;
        #pragma unroll
        for (int j = 0; j < 8; j++) { ls += f[j]; lq += f[j] * f[j]; }
        s[g] = ls; sq[g] = lq;
        if (g == 1) {
            #pragma unroll
            for (int j = 0; j < 8; j++) wk += g1v[j] * f[j];
        }
    }
    #pragma unroll
    for (int j = 0; j < 8; j++) { sg1 += g1v[j]; sb1 += b1v[j]; }

    #pragma unroll
    for (int g = 0; g < 6; ++g) { s[g] = wred64(s[g]); sq[g] = wred64(sq[g]); }
    wk = wred64(wk); sg1 = wred64(sg1); sb1 = wred64(sb1);

    if (lane == 0) {
        float* o = stats + (size_t)row * 16;
        const float inv = 1.0f / 512.0f;
        float mu[6], rs[6];
        #pragma unroll
        for (int g = 0; g < 6; ++g) {
            float m = s[g] * inv, e2 = sq[g] * inv;
            if (g == 1) { m *= INV_SQRT_H; e2 *= INV_SQRT_H * INV_SQRT_H; }
            float var = fmaxf(e2 - m * m, 0.0f);
            mu[g] = m; rs[g] = rsqrtf(var + 1e-5f);
        }
        #pragma unroll
        for (int g = 0; g < 6; ++g) { o[g] = mu[g]; o[6 + g] = rs[g]; }
        o[12] = rs[1] * (INV_SQRT_H * wk - mu[1] * sg1) + sb1;
    }
}

// ---- scanA: chunk-local scan from zero state. One thread per (chunk,b,h). ----
__global__ __launch_bounds__(128) void scanA_k(const u16* __restrict__ Z,
                                               const float* __restrict__ stats,
                                               const float* __restrict__ lngl,
                                               const float* __restrict__ lnbl,
                                               u16* __restrict__ nbuf,
                                               u16* __restrict__ pbuf,
                                               float* __restrict__ sumP,
                                               float* __restrict__ sumC,
                                               float* __restrict__ sumN) {
    const int b = blockIdx.y, chunk = blockIdx.z;
    const int h = blockIdx.x * 128 + threadIdx.x;
    __shared__ float sst[CH][16];
    for (int i = threadIdx.x; i < CH * 16; i += 128) {
        const int tc = i >> 4, j = i & 15;
        sst[tc][j] = stats[(size_t)((chunk * CH + tc) * 64 + b) * 16 + j];
    }
    float gg[4], gb[4];
    #pragma unroll
    for (int g = 0; g < 4; ++g) {
        gg[g] = lngl[(g + 1) * 512 + h];
        gb[g] = lnbl[(g + 1) * 512 + h];
    }
    __syncthreads();

    float c = 0.f, n = 0.f, P = 1.f;
    #pragma unroll 4
    for (int tc = 0; tc < CH; ++tc) {
        const int r = (chunk * CH + tc) * 64 + b;
        const u16* zr = Z + (size_t)r * NG + h;
        const float z1 = bu2f(zr[512]);
        const float z2 = bu2f(zr[1024]);
        const float z3 = bu2f(zr[1536]);
        const float z4 = bu2f(zr[2048]);
        const float kk = (z1 * INV_SQRT_H - sst[tc][1]) * sst[tc][7] * gg[0] + gb[0];
        const float vv = (z2 - sst[tc][2]) * sst[tc][8]  * gg[1] + gb[1];
        const float ii = sigm((z3 - sst[tc][3]) * sst[tc][9]  * gg[2] + gb[2]);
        const float ff = sigm((z4 - sst[tc][4]) * sst[tc][10] * gg[3] + gb[3]);
        c = ff * c + ii * (sst[tc][12] * vv);
        n = ff * n + ii * kk;
        P *= ff;
        nbuf[(size_t)r * 512 + h] = f2bf(n);
        pbuf[(size_t)r * 512 + h] = f2bf(P);
    }
    const size_t idx = ((size_t)chunk << 15) + (b << 9) + h;
    sumP[idx] = P; sumC[idx] = c; sumN[idx] = n;
}

// ---- scanB: exact fp32 combine across chunks; emits per-chunk incoming n0. ----
__global__ __launch_bounds__(256) void scanB_k(const float* __restrict__ sumP,
                                               const float* __restrict__ sumC,
                                               const float* __restrict__ sumN,
                                               float* __restrict__ n0buf,
                                               float* __restrict__ cstate,
                                               float* __restrict__ nstate,
                                               float* __restrict__ finals,
                                               int t0, int NC, int l) {
    const int idx = blockIdx.x * 256 + threadIdx.x;   // 0..32767
    float c, n;
    if (t0 == 0) { c = 0.f; n = 0.f; }
    else { c = cstate[idx]; n = nstate[idx]; }
    for (int ch = 0; ch < NC; ++ch) {
        const size_t o = ((size_t)ch << 15) + idx;
        n0buf[o] = n;
        const float P = sumP[o];
        c = sumC[o] + P * c;
        n = sumN[o] + P * n;
    }
    if (t0 + NC * CH == S_) {
        const int b = idx >> 9, h = idx & 511;
        const size_t so = ((size_t)l * B_ + b) * H_ + h;
        finals[(size_t)L_ * B_ * H_ + so] = c;       // c final (exact fp32 combine)
        finals[(size_t)2 * L_ * B_ * H_ + so] = n;   // n final
    } else {
        cstate[idx] = c; nstate[idx] = n;
    }
}

// ---- normh: one wave per (t,b) row. n = n_loc + P*n0; ||n|| reduce; h. ----
__global__ __launch_bounds__(256) void normh_k(const u16* __restrict__ Z,
                                               const u16* __restrict__ nbuf,
                                               const u16* __restrict__ pbuf,
                                               const float* __restrict__ n0buf,
                                               const float* __restrict__ stats,
                                               const float* __restrict__ lngl,
                                               const float* __restrict__ lnbl,
                                               float* __restrict__ hbuf,
                                               u16* __restrict__ aoutB,  // null for l==3
                                               float* __restrict__ outp, // null for l<3
                                               float* __restrict__ finals,
                                               int t0, int l) {
    const int wid = threadIdx.x >> 6, lane = threadIdx.x & 63;
    const int r = blockIdx.x * 4 + wid;
    const int h0 = lane * 8;

    float nl[8], pv[8];
    unp8(*(const uint4*)(nbuf + (size_t)r * 512 + h0), nl);
    unp8(*(const uint4*)(pbuf + (size_t)r * 512 + h0), pv);
    const float* n0r = n0buf + ((size_t)(r >> 10) << 15) + ((size_t)(r & 63) << 9) + h0;
    const float4 na = *(const float4*)(n0r);
    const float4 nb = *(const float4*)(n0r + 4);
    const float n0v[8] = {na.x, na.y, na.z, na.w, nb.x, nb.y, nb.z, nb.w};

    float nv[8], nsq = 0.f;
    #pragma unroll
    for (int j = 0; j < 8; j++) {
        nv[j] = fmaf(pv[j], n0v[j], nl[j]);
        nsq += nv[j] * nv[j];
    }
    nsq = wred64(nsq);
    const float rinv = 1.0f / (sqrtf(nsq) + 1e-8f);

    const u16* zr = Z + (size_t)r * NG;
    float z0[8], z5[8];
    unp8(*(const uint4*)(zr + h0), z0);
    unp8(*(const uint4*)(zr + 2560 + h0), z5);

    const float* st = stats + (size_t)r * 16;
    const float mu0 = st[0], rs0 = st[6], mu5 = st[5], rs5 = st[11];

    float g0[8], b0[8], g5[8], b5[8];
    #pragma unroll
    for (int j = 0; j < 8; j++) {
        g0[j] = lngl[h0 + j];        b0[j] = lnbl[h0 + j];
        g5[j] = lngl[2560 + h0 + j]; b5[j] = lnbl[2560 + h0 + j];
    }

    const int tl = r >> 6, b = r & 63;
    const int gr = t0 + tl;
    const size_t grow = (((size_t)gr * 64 + b) * 512) + h0;

    float hv[8];
    #pragma unroll
    for (int j = 0; j < 8; j++) {
        const float q  = (z0[j] - mu0) * rs0 * g0[j] + b0[j];
        const float oo = sigm((z5[j] - mu5) * rs5 * g5[j] + b5[j]);
        hv[j] = oo * tanhf_(q * nv[j] * rinv);
    }
    if (l > 0) {
        #pragma unroll
        for (int j = 0; j < 8; j++) hv[j] += hbuf[grow + j];
    }
    if (outp) {
        #pragma unroll
        for (int j = 0; j < 8; j++) outp[grow + j] = hv[j];
    } else {
        #pragma unroll
        for (int j = 0; j < 8; j++) hbuf[grow + j] = hv[j];
    }
    if (aoutB) *(uint4*)(aoutB + grow) = pck8(hv);

    if (gr == S_ - 1) {
        const size_t so = (((size_t)l * B_ + b) * 512) + h0;
        #pragma unroll
        for (int j = 0; j < 8; j++) finals[so + j] = hv[j];
    }
}

extern "C" void kernel_launch(void* const* d_in, const int* in_sizes, int n_in,
                              void* d_out, int out_size, void* d_ws, size_t ws_size,
                              hipStream_t stream) {
    const float* x   = (const float*)d_in[0];
    const float* W   = (const float*)d_in[1];
    const float* bia = (const float*)d_in[2];
    const float* lng = (const float*)d_in[3];
    const float* lnb = (const float*)d_in[4];
    float* out = (float*)d_out;

    const size_t WT_B = (size_t)L_ * 6 * H_ * F_ * 2;   // 12.58 MB
    const size_t A_B  = (size_t)RALL * F_ * 2;          // 16.78 MB
    const size_t ST_B = (size_t)RALL * 16 * 4;          // 1.05 MB
    const size_t CS_B = (size_t)B_ * H_ * 4;            // 128 KB
    const size_t HB_B = (size_t)RALL * H_ * 4;          // 33.55 MB
    auto zB  = [](int T) { return (size_t)T * B_ * NG * 2; };
    auto nB  = [](int T) { return (size_t)T * B_ * H_ * 2; };
    auto cxB = [](int T) { return (size_t)(T / CH) * B_ * H_ * 4; };
    const size_t base = WT_B + A_B + ST_B + 2 * CS_B + HB_B + 32768;

    int T = 16;
    const int cand[3] = {256, 64, 16};
    for (int i = 0; i < 3; i++) {
        const int Tc = cand[i];
        if (ws_size >= base + zB(Tc) + 2 * nB(Tc) + 4 * cxB(Tc)) { T = Tc; break; }
    }
    const int NC = T / CH;

    char* ws = (char*)d_ws;
    size_t off = 0;
    auto take = [&](size_t nb) { size_t o = off; off += (nb + 255) & ~(size_t)255; return o; };
    u16*   WT    = (u16*)  (ws + take(WT_B));
    u16*   Abf   = (u16*)  (ws + take(A_B));
    float* stats = (float*)(ws + take(ST_B));
    float* cs    = (float*)(ws + take(CS_B));
    float* ns    = (float*)(ws + take(CS_B));
    float* hbuf  = (float*)(ws + take(HB_B));
    u16*   zb    = (u16*)  (ws + take(zB(T)));
    u16*   nbuf  = (u16*)  (ws + take(nB(T)));
    u16*   pbuf  = (u16*)  (ws + take(nB(T)));
    float* sumP  = (float*)(ws + take(cxB(T)));
    float* sumC  = (float*)(ws + take(cxB(T)));
    float* sumN  = (float*)(ws + take(cxB(T)));
    float* n0buf = (float*)(ws + take(cxB(T)));

    convw_k<<<dim3(16, 16, 24), dim3(32, 8), 0, stream>>>(W, WT);
    convx_k<<<dim3(RALL * F_ / 4 / 256), dim3(256), 0, stream>>>(x, Abf);

    float* finals = out + (size_t)S_ * B_ * H_;
    for (int l = 0; l < L_; ++l) {
        const u16*   WTl   = WT  + (size_t)l * 6 * H_ * F_;
        const float* biasl = bia + (size_t)l * NG;
        const float* lngl  = lng + (size_t)l * 6 * H_;
        const float* lnbl  = lnb + (size_t)l * 6 * H_;
        for (int j = 0; j < S_ / T; ++j) {
            const int t0 = j * T, arow0 = t0 * B_;
            const int rows = T * B_;
            gemm_k<<<dim3(24, rows / 128), dim3(256), 0, stream>>>(Abf, WTl, zb, biasl, arow0);
            stats_k<<<dim3(rows / 4), dim3(256), 0, stream>>>(zb, lngl + H_, lnbl + H_, stats);
            scanA_k<<<dim3(4, B_, NC), dim3(128), 0, stream>>>(zb, stats, lngl, lnbl,
                                                               nbuf, pbuf, sumP, sumC, sumN);
            scanB_k<<<dim3(128), dim3(256), 0, stream>>>(sumP, sumC, sumN, n0buf,
                                                         cs, ns, finals, t0, NC, l);
            normh_k<<<dim3(rows / 4), dim3(256), 0, stream>>>(zb, nbuf, pbuf, n0buf, stats,
                                                              lngl, lnbl, hbuf,
                                                              (l < 3) ? Abf : (u16*)nullptr,
                                                              (l == 3) ? out : (float*)nullptr,
                                                              finals, t0, l);
        }
    }
}

// Round 6
// 632.627 us; speedup vs baseline: 1.2768x; 1.0751x over previous
//
#include <hip/hip_runtime.h>

// mLSTM  S=256 B=64 F=H=512 L=4
// v6: gemm rebuilt on 32x32x16 MFMA (half the MFMA issue slots + smaller frags),
//     stats_k reads only gates 1-4, normh computes gates 0/5 stats inline.
//   gemm_k  : Z = A @ W^T + bias (bf16 MFMA 32x32x16, 128x128 tile, BK=64, swizzled)
//   stats_k : LN mu/rstd for gates 1-4 + sum_k
//   scanA_k : chunk-local scans (16-step), P_t = prod f stored
//   scanB_k : exact fp32 cross-chunk combine -> n0/chunk
//   normh_k : inline stats for q,o; n_t = n_loc + P_t*n0; ||n||; h = o*tanh(q*n_hat)+res

typedef unsigned short u16;
typedef unsigned int   u32;
typedef short s8v  __attribute__((ext_vector_type(8)));   // 8 x bf16 (4 VGPRs)
typedef float f16v __attribute__((ext_vector_type(16)));  // 32x32 MFMA accum

#define S_    256
#define B_    64
#define F_    512
#define H_    512
#define L_    4
#define NG    3072          // 6*H
#define RALL  16384         // S*B
#define CH    16            // scan chunk length
#define INV_SQRT_H 0.044194173824159216f

__device__ __forceinline__ float bu2f(u16 u) {
    union { u32 i; float f; } z; z.i = ((u32)u) << 16; return z.f;
}
__device__ __forceinline__ u16 f2bf(float f) {
    union { float f; u32 i; } z; z.f = f;
    u32 r = (z.i + 0x7FFFu + ((z.i >> 16) & 1u)) >> 16;
    return (u16)r;
}
__device__ __forceinline__ float sigm(float x)  { return 1.0f / (1.0f + __expf(-x)); }
__device__ __forceinline__ float tanhf_(float x){ return 2.0f / (1.0f + __expf(-2.0f * x)) - 1.0f; }
__device__ __forceinline__ float wred64(float v) {
    #pragma unroll
    for (int m = 1; m < 64; m <<= 1) v += __shfl_xor(v, m);
    return v;
}
__device__ __forceinline__ void gl_lds16(const u16* g, u16* l) {
    __builtin_amdgcn_global_load_lds((const __attribute__((address_space(1))) u32*)g,
                                     (__attribute__((address_space(3))) u32*)l, 16, 0, 0);
}
__device__ __forceinline__ void unp8(uint4 u, float* f) {
    f[0] = bu2f((u16)(u.x & 0xffff)); f[1] = bu2f((u16)(u.x >> 16));
    f[2] = bu2f((u16)(u.y & 0xffff)); f[3] = bu2f((u16)(u.y >> 16));
    f[4] = bu2f((u16)(u.z & 0xffff)); f[5] = bu2f((u16)(u.z >> 16));
    f[6] = bu2f((u16)(u.w & 0xffff)); f[7] = bu2f((u16)(u.w >> 16));
}
__device__ __forceinline__ uint4 pck8(const float* f) {
    uint4 u;
    u.x = (u32)f2bf(f[0]) | ((u32)f2bf(f[1]) << 16);
    u.y = (u32)f2bf(f[2]) | ((u32)f2bf(f[3]) << 16);
    u.z = (u32)f2bf(f[4]) | ((u32)f2bf(f[5]) << 16);
    u.w = (u32)f2bf(f[6]) | ((u32)f2bf(f[7]) << 16);
    return u;
}

// ---- W [L,6,F,H] fp32 -> WT [L,6,H,F] bf16 (transpose via LDS tile) ----
__global__ void convw_k(const float* __restrict__ W, u16* __restrict__ WT) {
    __shared__ float tile[32][33];
    const int lg = blockIdx.z;                  // 0..23
    const int h0 = blockIdx.x * 32, f0 = blockIdx.y * 32;
    const float* Wb = W  + (size_t)lg * F_ * H_;
    u16*        WTb = WT + (size_t)lg * F_ * H_;
    const int tx = threadIdx.x, ty = threadIdx.y;  // 32x8
    #pragma unroll
    for (int i = 0; i < 32; i += 8)
        tile[ty + i][tx] = Wb[(size_t)(f0 + ty + i) * H_ + h0 + tx];
    __syncthreads();
    #pragma unroll
    for (int i = 0; i < 32; i += 8)
        WTb[(size_t)(h0 + ty + i) * F_ + f0 + tx] = f2bf(tile[tx][ty + i]);
}

// ---- x fp32 -> A bf16 ----
__global__ void convx_k(const float* __restrict__ x, u16* __restrict__ A) {
    const int i = blockIdx.x * 256 + threadIdx.x;   // covers RALL*F/4 exactly
    float4 v = ((const float4*)x)[i];
    u32 lo = (u32)f2bf(v.x) | ((u32)f2bf(v.y) << 16);
    u32 hi = (u32)f2bf(v.z) | ((u32)f2bf(v.w) << 16);
    ((uint2*)A)[i] = make_uint2(lo, hi);
}

// ---- GEMM: Z[m,3072] = A @ WT^T + bias. 128x128 tile, BK=64, 32x32x16 MFMA. ----
// LDS: 128 rows x 8 slots of 16B; slot s of row r holds chunk g = s ^ (r&7).
// Wave tile 64x64 = 2x2 of 32x32. A-frag: m=lane&31, k=(lane>>5)*8+j.
__global__ __launch_bounds__(256) void gemm_k(const u16* __restrict__ A,
                                              const u16* __restrict__ BT,
                                              u16* __restrict__ Z,
                                              const float* __restrict__ bias,
                                              int arow0) {
    __shared__ u16 lsA[128 * 64];
    __shared__ u16 lsB[128 * 64];
    const int t = threadIdx.x;
    const int ntile = blockIdx.x;                  // 0..23
    const int mtile = blockIdx.y;
    const int ncol0 = ntile * 128;
    const u16* Ab = A  + (size_t)(arow0 + mtile * 128) * F_;
    const u16* Bb = BT + (size_t)ntile * 128 * F_;
    const int lane = t & 63, wv = t >> 6;

    f16v acc[2][2];
    #pragma unroll
    for (int i = 0; i < 2; i++)
        #pragma unroll
        for (int j = 0; j < 2; j++) acc[i][j] = 0.0f;

    const int wm = (wv >> 1) * 64, wn = (wv & 1) * 64;
    const int rl = lane & 31, hi = lane >> 5;      // row-in-tile, k-half
    const int r7 = rl & 7;

    // staging: 4 chunks each for A and B per thread per kb-iter
    int goff[4];
    #pragma unroll
    for (int s = 0; s < 4; s++) {
        const int c = t + 256 * s;
        const int row = c >> 3, slot = c & 7;
        const int g = slot ^ (row & 7);
        goff[s] = row * F_ + g * 8;
    }

    for (int kb = 0; kb < 8; ++kb) {
        const int kofs = kb * 64;
        #pragma unroll
        for (int s = 0; s < 4; s++) {
            const int c = t + 256 * s;
            gl_lds16(Ab + goff[s] + kofs, lsA + c * 8);
            gl_lds16(Bb + goff[s] + kofs, lsB + c * 8);
        }
        __syncthreads();
        #pragma unroll
        for (int s = 0; s < 4; ++s) {               // 4 k-steps of 16
            const int slot = ((s << 1) + hi) ^ r7;
            s8v fa[2], fb[2];
            #pragma unroll
            for (int i = 0; i < 2; i++)
                fa[i] = *(const s8v*)(lsA + (wm + i * 32 + rl) * 64 + slot * 8);
            #pragma unroll
            for (int j = 0; j < 2; j++)
                fb[j] = *(const s8v*)(lsB + (wn + j * 32 + rl) * 64 + slot * 8);
            #pragma unroll
            for (int i = 0; i < 2; i++)
                #pragma unroll
                for (int j = 0; j < 2; j++)
                    acc[i][j] = __builtin_amdgcn_mfma_f32_32x32x16_bf16(fa[i], fb[j], acc[i][j], 0, 0, 0);
        }
        __syncthreads();
    }

    // epilogue: C/D layout col=lane&31, row=(reg&3)+8*(reg>>2)+4*(lane>>5)
    #pragma unroll
    for (int j = 0; j < 2; j++) {
        const int col = ncol0 + wn + j * 32 + rl;
        const float bv = bias[col];
        #pragma unroll
        for (int i = 0; i < 2; i++) {
            const int mbase = mtile * 128 + wm + i * 32 + hi * 4;
            #pragma unroll
            for (int reg = 0; reg < 16; reg++) {
                const int row = mbase + (reg & 3) + 8 * (reg >> 2);
                Z[(size_t)row * NG + col] = f2bf(acc[i][j][reg] + bv);
            }
        }
    }
}

// ---- stats: per row (t,b): LN mu/rstd for gates 1-4 + sum_k. One wave per row. ----
__global__ __launch_bounds__(256) void stats_k(const u16* __restrict__ Z,
                                               const float* __restrict__ lng1,
                                               const float* __restrict__ lnb1,
                                               float* __restrict__ stats) {
    const int wid = threadIdx.x >> 6, lane = threadIdx.x & 63;
    const int row = blockIdx.x * 4 + wid;
    const u16* zr = Z + (size_t)row * NG + lane * 8;

    float g1v[8], b1v[8];
    #pragma unroll
    for (int j = 0; j < 8; j++) { g1v[j] = lng1[lane * 8 + j]; b1v[j] = lnb1[lane * 8 + j]; }

    float s[4], sq[4], wk = 0.f, sg1 = 0.f, sb1 = 0.f;
    #pragma unroll
    for (int g = 0; g < 4; ++g) {
        uint4 u = *(const uint4*)(zr + (g + 1) * 512);
        float f[8];
        unp8(u, f);
        float ls = 0.f, lq = 0.f;
        #pragma unroll
        for (int j = 0; j < 8; j++) { ls += f[j]; lq += f[j] * f[j]; }
        s[g] = ls; sq[g] = lq;
        if (g == 0) {
            #pragma unroll
            for (int j = 0; j < 8; j++) wk += g1v[j] * f[j];
        }
    }
    #pragma unroll
    for (int j = 0; j < 8; j++) { sg1 += g1v[j]; sb1 += b1v[j]; }

    #pragma unroll
    for (int g = 0; g < 4; ++g) { s[g] = wred64(s[g]); sq[g] = wred64(sq[g]); }
    wk = wred64(wk); sg1 = wred64(sg1); sb1 = wred64(sb1);

    if (lane == 0) {
        float* o = stats + (size_t)row * 16;
        const float inv = 1.0f / 512.0f;
        float mu1 = 0.f, rs1 = 0.f;
        #pragma unroll
        for (int g = 0; g < 4; ++g) {
            float m = s[g] * inv, e2 = sq[g] * inv;
            if (g == 0) { m *= INV_SQRT_H; e2 *= INV_SQRT_H * INV_SQRT_H; }
            const float rs = rsqrtf(fmaxf(e2 - m * m, 0.0f) + 1e-5f);
            o[1 + g] = m; o[7 + g] = rs;
            if (g == 0) { mu1 = m; rs1 = rs; }
        }
        o[12] = rs1 * (INV_SQRT_H * wk - mu1 * sg1) + sb1;
    }
}

// ---- scanA: chunk-local scan from zero state. One thread per (chunk,b,h). ----
__global__ __launch_bounds__(128) void scanA_k(const u16* __restrict__ Z,
                                               const float* __restrict__ stats,
                                               const float* __restrict__ lngl,
                                               const float* __restrict__ lnbl,
                                               u16* __restrict__ nbuf,
                                               u16* __restrict__ pbuf,
                                               float* __restrict__ sumP,
                                               float* __restrict__ sumC,
                                               float* __restrict__ sumN) {
    const int b = blockIdx.y, chunk = blockIdx.z;
    const int h = blockIdx.x * 128 + threadIdx.x;
    __shared__ float sst[CH][16];
    for (int i = threadIdx.x; i < CH * 16; i += 128) {
        const int tc = i >> 4, j = i & 15;
        sst[tc][j] = stats[(size_t)((chunk * CH + tc) * 64 + b) * 16 + j];
    }
    float gg[4], gb[4];
    #pragma unroll
    for (int g = 0; g < 4; ++g) {
        gg[g] = lngl[(g + 1) * 512 + h];
        gb[g] = lnbl[(g + 1) * 512 + h];
    }
    __syncthreads();

    float c = 0.f, n = 0.f, P = 1.f;
    #pragma unroll 4
    for (int tc = 0; tc < CH; ++tc) {
        const int r = (chunk * CH + tc) * 64 + b;
        const u16* zr = Z + (size_t)r * NG + h;
        const float z1 = bu2f(zr[512]);
        const float z2 = bu2f(zr[1024]);
        const float z3 = bu2f(zr[1536]);
        const float z4 = bu2f(zr[2048]);
        const float kk = (z1 * INV_SQRT_H - sst[tc][1]) * sst[tc][7] * gg[0] + gb[0];
        const float vv = (z2 - sst[tc][2]) * sst[tc][8]  * gg[1] + gb[1];
        const float ii = sigm((z3 - sst[tc][3]) * sst[tc][9]  * gg[2] + gb[2]);
        const float ff = sigm((z4 - sst[tc][4]) * sst[tc][10] * gg[3] + gb[3]);
        c = ff * c + ii * (sst[tc][12] * vv);
        n = ff * n + ii * kk;
        P *= ff;
        nbuf[(size_t)r * 512 + h] = f2bf(n);
        pbuf[(size_t)r * 512 + h] = f2bf(P);
    }
    const size_t idx = ((size_t)chunk << 15) + (b << 9) + h;
    sumP[idx] = P; sumC[idx] = c; sumN[idx] = n;
}

// ---- scanB: exact fp32 combine across chunks; emits per-chunk incoming n0. ----
__global__ __launch_bounds__(256) void scanB_k(const float* __restrict__ sumP,
                                               const float* __restrict__ sumC,
                                               const float* __restrict__ sumN,
                                               float* __restrict__ n0buf,
                                               float* __restrict__ cstate,
                                               float* __restrict__ nstate,
                                               float* __restrict__ finals,
                                               int t0, int NC, int l) {
    const int idx = blockIdx.x * 256 + threadIdx.x;   // 0..32767
    float c, n;
    if (t0 == 0) { c = 0.f; n = 0.f; }
    else { c = cstate[idx]; n = nstate[idx]; }
    for (int ch = 0; ch < NC; ++ch) {
        const size_t o = ((size_t)ch << 15) + idx;
        n0buf[o] = n;
        const float P = sumP[o];
        c = sumC[o] + P * c;
        n = sumN[o] + P * n;
    }
    if (t0 + NC * CH == S_) {
        const int b = idx >> 9, h = idx & 511;
        const size_t so = ((size_t)l * B_ + b) * H_ + h;
        finals[(size_t)L_ * B_ * H_ + so] = c;       // c final (exact fp32 combine)
        finals[(size_t)2 * L_ * B_ * H_ + so] = n;   // n final
    } else {
        cstate[idx] = c; nstate[idx] = n;
    }
}

// ---- normh: one wave per (t,b) row. Inline stats for gates 0,5. ----
__global__ __launch_bounds__(256) void normh_k(const u16* __restrict__ Z,
                                               const u16* __restrict__ nbuf,
                                               const u16* __restrict__ pbuf,
                                               const float* __restrict__ n0buf,
                                               const float* __restrict__ lngl,
                                               const float* __restrict__ lnbl,
                                               float* __restrict__ hbuf,
                                               u16* __restrict__ aoutB,  // null for l==3
                                               float* __restrict__ outp, // null for l<3
                                               float* __restrict__ finals,
                                               int t0, int l) {
    const int wid = threadIdx.x >> 6, lane = threadIdx.x & 63;
    const int r = blockIdx.x * 4 + wid;
    const int h0 = lane * 8;

    float nl[8], pv[8];
    unp8(*(const uint4*)(nbuf + (size_t)r * 512 + h0), nl);
    unp8(*(const uint4*)(pbuf + (size_t)r * 512 + h0), pv);
    const float* n0r = n0buf + ((size_t)(r >> 10) << 15) + ((size_t)(r & 63) << 9) + h0;
    const float4 na = *(const float4*)(n0r);
    const float4 nb = *(const float4*)(n0r + 4);
    const float n0v[8] = {na.x, na.y, na.z, na.w, nb.x, nb.y, nb.z, nb.w};

    const u16* zr = Z + (size_t)r * NG;
    float z0[8], z5[8];
    unp8(*(const uint4*)(zr + h0), z0);
    unp8(*(const uint4*)(zr + 2560 + h0), z5);

    // combined reductions: ||n||^2 and gate-0/5 LN stats
    float nsq = 0.f, s0 = 0.f, q0 = 0.f, s5 = 0.f, q5 = 0.f;
    float nv[8];
    #pragma unroll
    for (int j = 0; j < 8; j++) {
        nv[j] = fmaf(pv[j], n0v[j], nl[j]);
        nsq += nv[j] * nv[j];
        s0 += z0[j]; q0 += z0[j] * z0[j];
        s5 += z5[j]; q5 += z5[j] * z5[j];
    }
    nsq = wred64(nsq);
    s0 = wred64(s0); q0 = wred64(q0);
    s5 = wred64(s5); q5 = wred64(q5);
    const float rinv = 1.0f / (sqrtf(nsq) + 1e-8f);
    const float inv = 1.0f / 512.0f;
    const float mu0 = s0 * inv, mu5 = s5 * inv;
    const float rs0 = rsqrtf(fmaxf(q0 * inv - mu0 * mu0, 0.0f) + 1e-5f);
    const float rs5 = rsqrtf(fmaxf(q5 * inv - mu5 * mu5, 0.0f) + 1e-5f);

    float g0[8], b0[8], g5[8], b5[8];
    #pragma unroll
    for (int j = 0; j < 8; j++) {
        g0[j] = lngl[h0 + j];        b0[j] = lnbl[h0 + j];
        g5[j] = lngl[2560 + h0 + j]; b5[j] = lnbl[2560 + h0 + j];
    }

    const int tl = r >> 6, b = r & 63;
    const int gr = t0 + tl;
    const size_t grow = (((size_t)gr * 64 + b) * 512) + h0;

    float hv[8];
    #pragma unroll
    for (int j = 0; j < 8; j++) {
        const float q  = (z0[j] - mu0) * rs0 * g0[j] + b0[j];
        const float oo = sigm((z5[j] - mu5) * rs5 * g5[j] + b5[j]);
        hv[j] = oo * tanhf_(q * nv[j] * rinv);
    }
    if (l > 0) {
        #pragma unroll
        for (int j = 0; j < 8; j++) hv[j] += hbuf[grow + j];
    }
    if (outp) {
        #pragma unroll
        for (int j = 0; j < 8; j++) outp[grow + j] = hv[j];
    } else {
        #pragma unroll
        for (int j = 0; j < 8; j++) hbuf[grow + j] = hv[j];
    }
    if (aoutB) *(uint4*)(aoutB + grow) = pck8(hv);

    if (gr == S_ - 1) {
        const size_t so = (((size_t)l * B_ + b) * 512) + h0;
        #pragma unroll
        for (int j = 0; j < 8; j++) finals[so + j] = hv[j];
    }
}

extern "C" void kernel_launch(void* const* d_in, const int* in_sizes, int n_in,
                              void* d_out, int out_size, void* d_ws, size_t ws_size,
                              hipStream_t stream) {
    const float* x   = (const float*)d_in[0];
    const float* W   = (const float*)d_in[1];
    const float* bia = (const float*)d_in[2];
    const float* lng = (const float*)d_in[3];
    const float* lnb = (const float*)d_in[4];
    float* out = (float*)d_out;

    const size_t WT_B = (size_t)L_ * 6 * H_ * F_ * 2;   // 12.58 MB
    const size_t A_B  = (size_t)RALL * F_ * 2;          // 16.78 MB
    const size_t ST_B = (size_t)RALL * 16 * 4;          // 1.05 MB
    const size_t CS_B = (size_t)B_ * H_ * 4;            // 128 KB
    const size_t HB_B = (size_t)RALL * H_ * 4;          // 33.55 MB
    auto zB  = [](int T) { return (size_t)T * B_ * NG * 2; };
    auto nB  = [](int T) { return (size_t)T * B_ * H_ * 2; };
    auto cxB = [](int T) { return (size_t)(T / CH) * B_ * H_ * 4; };
    const size_t base = WT_B + A_B + ST_B + 2 * CS_B + HB_B + 32768;

    int T = 16;
    const int cand[3] = {256, 64, 16};
    for (int i = 0; i < 3; i++) {
        const int Tc = cand[i];
        if (ws_size >= base + zB(Tc) + 2 * nB(Tc) + 4 * cxB(Tc)) { T = Tc; break; }
    }
    const int NC = T / CH;

    char* ws = (char*)d_ws;
    size_t off = 0;
    auto take = [&](size_t nb) { size_t o = off; off += (nb + 255) & ~(size_t)255; return o; };
    u16*   WT    = (u16*)  (ws + take(WT_B));
    u16*   Abf   = (u16*)  (ws + take(A_B));
    float* stats = (float*)(ws + take(ST_B));
    float* cs    = (float*)(ws + take(CS_B));
    float* ns    = (float*)(ws + take(CS_B));
    float* hbuf  = (float*)(ws + take(HB_B));
    u16*   zb    = (u16*)  (ws + take(zB(T)));
    u16*   nbuf  = (u16*)  (ws + take(nB(T)));
    u16*   pbuf  = (u16*)  (ws + take(nB(T)));
    float* sumP  = (float*)(ws + take(cxB(T)));
    float* sumC  = (float*)(ws + take(cxB(T)));
    float* sumN  = (float*)(ws + take(cxB(T)));
    float* n0buf = (float*)(ws + take(cxB(T)));

    convw_k<<<dim3(16, 16, 24), dim3(32, 8), 0, stream>>>(W, WT);
    convx_k<<<dim3(RALL * F_ / 4 / 256), dim3(256), 0, stream>>>(x, Abf);

    float* finals = out + (size_t)S_ * B_ * H_;
    for (int l = 0; l < L_; ++l) {
        const u16*   WTl   = WT  + (size_t)l * 6 * H_ * F_;
        const float* biasl = bia + (size_t)l * NG;
        const float* lngl  = lng + (size_t)l * 6 * H_;
        const float* lnbl  = lnb + (size_t)l * 6 * H_;
        for (int j = 0; j < S_ / T; ++j) {
            const int t0 = j * T, arow0 = t0 * B_;
            const int rows = T * B_;
            gemm_k<<<dim3(24, rows / 128), dim3(256), 0, stream>>>(Abf, WTl, zb, biasl, arow0);
            stats_k<<<dim3(rows / 4), dim3(256), 0, stream>>>(zb, lngl + H_, lnbl + H_, stats);
            scanA_k<<<dim3(4, B_, NC), dim3(128), 0, stream>>>(zb, stats, lngl, lnbl,
                                                               nbuf, pbuf, sumP, sumC, sumN);
            scanB_k<<<dim3(128), dim3(256), 0, stream>>>(sumP, sumC, sumN, n0buf,
                                                         cs, ns, finals, t0, NC, l);
            normh_k<<<dim3(rows / 4), dim3(256), 0, stream>>>(zb, nbuf, pbuf, n0buf,
                                                              lngl, lnbl, hbuf,
                                                              (l < 3) ? Abf : (u16*)nullptr,
                                                              (l == 3) ? out : (float*)nullptr,
                                                              finals, t0, l);
        }
    }
}